// Round 3
// baseline (155.092 us; speedup 1.0000x reference)
//
#include <hip/hip_runtime.h>
#include <math.h>

#define NSAMP 1024
#define DIM   64
#define NLAYER 3

#define JC 64                    // j rows per chunk (LDS tile)
#define JS (NSAMP / JC)          // 16 j-chunks
#define NT 64                    // n rows per pair-tile
#define RT 4                     // n rows per thread
#define NTILES (NSAMP / NT)      // 16 n-tiles

// workspace layout (float index)
#define MU_OFF   0
#define INV_OFF  (NLAYER * NSAMP * DIM)        // 196608
#define PART_OFF (2 * NLAYER * NSAMP * DIM)    // 393216
#define NPART    (NTILES * JS * NLAYER)        // 768
#define CNT_OFF  (PART_OFF + NPART)            // 2 ints: [0]=barrier, [1]=ticket
#define WS_REQ   ((size_t)(CNT_OFF + 2) * sizeof(float))

// ---------------------------------------------------------------------------
// ONE dispatch: head -> grid barrier -> pairwise -> ticketed final reduce.
// 768 blocks x 256 threads, guaranteed co-resident (3 blocks/CU: 17.4KB LDS,
// ~100 VGPR, 12 waves/CU) so the software grid barrier cannot deadlock.
__global__ __launch_bounds__(256) void ib_one(
    const float* __restrict__ fea0, const float* __restrict__ fea1,
    const float* __restrict__ fea2, const float* __restrict__ fea3,
    const float* __restrict__ W_mu, const float* __restrict__ b_mu,
    const float* __restrict__ W_var, const float* __restrict__ b_var,
    float* __restrict__ ws, float* __restrict__ out)
{
    const int b     = blockIdx.x;          // 0..767
    const int layer = b >> 8;
    const int sub   = b & 255;
    const int tid   = threadIdx.x;

    const float* __restrict__ fr_p =
        (layer == 0) ? fea0 : (layer == 1) ? fea1 : fea2;   // reference
    const float* __restrict__ fs_p =
        (layer == 0) ? fea1 : (layer == 1) ? fea2 : fea3;   // student

    int* cnts = (int*)(ws + CNT_OFF);

    __shared__ float  fs[4][DIM];          // 1 KB   (head phase)
    __shared__ float4 fr[JC][DIM / 4];     // 16 KB  (pair phase)
    __shared__ float  wsum[4];
    __shared__ int    winner;

    // ---------------- phase A: head for my 4 rows ----------------
    const int d  = tid & 63;
    const int nl = tid >> 6;
    const int hn = sub * 4 + nl;

    fs[nl][d] = fs_p[hn * DIM + d];
    __syncthreads();

    const float4* __restrict__ wm = (const float4*)(W_mu + (layer * DIM + d) * DIM);
    const float4* __restrict__ wv = (const float4*)(W_var + (layer * DIM + d) * DIM);
    float am = 0.f, av = 0.f;
#pragma unroll
    for (int k = 0; k < DIM / 4; ++k) {
        const float4 m4 = wm[k];
        const float4 v4 = wv[k];
        const float f0 = fs[nl][k * 4 + 0];
        const float f1 = fs[nl][k * 4 + 1];
        const float f2 = fs[nl][k * 4 + 2];
        const float f3 = fs[nl][k * 4 + 3];
        am = fmaf(f0, m4.x, am); am = fmaf(f1, m4.y, am);
        am = fmaf(f2, m4.z, am); am = fmaf(f3, m4.w, am);
        av = fmaf(f0, v4.x, av); av = fmaf(f1, v4.y, av);
        av = fmaf(f2, v4.z, av); av = fmaf(f3, v4.w, av);
    }
    const float muh = am + b_mu[layer * DIM + d];
    const float x   = av + b_var[layer * DIM + d];
    const float sp  = fmaxf(x, 0.f) + log1pf(expf(-fabsf(x)));
    const float var = sp * 0.1f + 1e-6f;

    const int o = (layer * NSAMP + hn) * DIM + d;
    ws[MU_OFF + o]  = muh;
    ws[INV_OFF + o] = 1.0f / var;

    // ---------------- pre-stage my pair j-tile (independent of heads) -------
    const int ntile = sub & 15;
    const int jc    = sub >> 4;
    const float4* __restrict__ src = (const float4*)(fr_p + jc * JC * DIM);
#pragma unroll
    for (int t = 0; t < 4; ++t)
        ((float4*)fr)[tid + t * 256] = src[tid + t * 256];

    // ---------------- grid barrier (all 768 blocks co-resident) -------------
    __syncthreads();
    if (tid == 0) {
        __hip_atomic_fetch_add(&cnts[0], 1, __ATOMIC_RELEASE,
                               __HIP_MEMORY_SCOPE_AGENT);
        while (__hip_atomic_load(&cnts[0], __ATOMIC_ACQUIRE,
                                 __HIP_MEMORY_SCOPE_AGENT) < NPART)
            __builtin_amdgcn_s_sleep(2);
    }
    __syncthreads();

    // ---------------- phase B: pairwise for (layer, ntile, jc) --------------
    const int q  = tid & 15;
    const int rg = tid >> 4;
    const int n0 = ntile * NT + rg * RT;
    const int d0 = q * 4;

    const float4* __restrict__ mup =
        (const float4*)(ws + MU_OFF + (layer * NSAMP + n0) * DIM + d0);
    float4 mu4[RT];
#pragma unroll
    for (int r = 0; r < RT; ++r) mu4[r] = mup[r * (DIM / 4)];

    float4 ps[RT];
#pragma unroll
    for (int r = 0; r < RT; ++r) ps[r] = make_float4(0.f, 0.f, 0.f, 0.f);

#pragma unroll 8
    for (int j = 0; j < JC; ++j) {
        const float4 f = fr[j][q];
#pragma unroll
        for (int r = 0; r < RT; ++r) {
            ps[r].x += fabsf(f.x - mu4[r].x);
            ps[r].y += fabsf(f.y - mu4[r].y);
            ps[r].z += fabsf(f.z - mu4[r].z);
            ps[r].w += fabsf(f.w - mu4[r].w);
        }
    }

    const float4* __restrict__ ivp =
        (const float4*)(ws + INV_OFF + (layer * NSAMP + n0) * DIM + d0);
    const float inv_n = 1.0f / (float)NSAMP;
    float s = 0.f;
    if (jc == 0) {
        const float4* __restrict__ fsp = (const float4*)(fr_p + n0 * DIM + d0);
#pragma unroll
        for (int r = 0; r < RT; ++r) {
            const float4 iv = ivp[r * (DIM / 4)];
            const float4 a  = fsp[r * (DIM / 4)];
            s += (ps[r].x * inv_n - fabsf(mu4[r].x - a.x)) * iv.x;
            s += (ps[r].y * inv_n - fabsf(mu4[r].y - a.y)) * iv.y;
            s += (ps[r].z * inv_n - fabsf(mu4[r].z - a.z)) * iv.z;
            s += (ps[r].w * inv_n - fabsf(mu4[r].w - a.w)) * iv.w;
        }
    } else {
#pragma unroll
        for (int r = 0; r < RT; ++r) {
            const float4 iv = ivp[r * (DIM / 4)];
            s += ps[r].x * inv_n * iv.x;
            s += ps[r].y * inv_n * iv.y;
            s += ps[r].z * inv_n * iv.z;
            s += ps[r].w * inv_n * iv.w;
        }
    }

    // block reduction (deterministic)
#pragma unroll
    for (int off = 32; off > 0; off >>= 1)
        s += __shfl_down(s, off, 64);
    if ((tid & 63) == 0) wsum[tid >> 6] = s;
    __syncthreads();

    // ---------------- ticket: last block does the final fixed-order sum -----
    if (tid == 0) {
        ws[PART_OFF + b] = wsum[0] + wsum[1] + wsum[2] + wsum[3];
        __threadfence();
        const int old = __hip_atomic_fetch_add(&cnts[1], 1, __ATOMIC_ACQ_REL,
                                               __HIP_MEMORY_SCOPE_AGENT);
        winner = (old == NPART - 1);
    }
    __syncthreads();

    if (winner) {
        // fixed-order final reduction: identical order every call
        float v = ws[PART_OFF + tid] + ws[PART_OFF + tid + 256]
                + ws[PART_OFF + tid + 512];
#pragma unroll
        for (int off = 32; off > 0; off >>= 1)
            v += __shfl_down(v, off, 64);
        if ((tid & 63) == 0) wsum[tid >> 6] = v;
        __syncthreads();
        if (tid == 0)
            out[0] = (wsum[0] + wsum[1] + wsum[2] + wsum[3]) * inv_n;
    }
}

// ---------------------------------------------------------------------------
// fallback path (tiny ws): round-1 fused kernel + final reduce
__global__ __launch_bounds__(256) void ib_fused(
    const float* __restrict__ fea0, const float* __restrict__ fea1,
    const float* __restrict__ fea2, const float* __restrict__ fea3,
    const float* __restrict__ W_mu, const float* __restrict__ b_mu,
    const float* __restrict__ W_var, const float* __restrict__ b_var,
    float* __restrict__ partials)
{
    const int layer = blockIdx.y;
    const float* feas[4] = {fea0, fea1, fea2, fea3};
    const float* __restrict__ fr_p = feas[layer];
    const float* __restrict__ fs_p = feas[layer + 1];

    const int tid = threadIdx.x;
    const int d   = tid & 63;
    const int nl  = tid >> 6;
    const int n   = blockIdx.x * 4 + nl;

    __shared__ float fs[4][DIM];
    __shared__ float fr[JC][DIM];
    __shared__ float wsum[4];

    fs[nl][d] = fs_p[n * DIM + d];
    __syncthreads();

    const float* __restrict__ wm = W_mu + (layer * DIM + d) * DIM;
    const float* __restrict__ wv = W_var + (layer * DIM + d) * DIM;
    float am = 0.f, av = 0.f;
#pragma unroll
    for (int k = 0; k < DIM; ++k) {
        const float f = fs[nl][k];
        am = fmaf(f, wm[k], am);
        av = fmaf(f, wv[k], av);
    }
    const float mu = am + b_mu[layer * DIM + d];
    const float x  = av + b_var[layer * DIM + d];
    const float sp  = fmaxf(x, 0.f) + log1pf(expf(-fabsf(x)));
    const float var = sp * 0.1f + 1e-6f;

    float psum = 0.f;
    for (int j0 = 0; j0 < NSAMP; j0 += JC) {
        __syncthreads();
#pragma unroll
        for (int t = 0; t < (JC * DIM) / 256; ++t) {
            const int l = tid + t * 256;
            ((float*)fr)[l] = fr_p[j0 * DIM + l];
        }
        __syncthreads();
#pragma unroll
        for (int j = 0; j < JC; ++j)
            psum += fabsf(fr[j][d] - mu);
    }

    const float frnd = fr_p[n * DIM + d];
    float t = (psum * (1.0f / NSAMP) - fabsf(mu - frnd)) / var;

#pragma unroll
    for (int off = 32; off > 0; off >>= 1)
        t += __shfl_down(t, off, 64);
    if ((tid & 63) == 0) wsum[tid >> 6] = t;
    __syncthreads();
    if (tid == 0)
        partials[blockIdx.y * gridDim.x + blockIdx.x] =
            wsum[0] + wsum[1] + wsum[2] + wsum[3];
}

__global__ __launch_bounds__(256) void ib_final(
    const float* __restrict__ partials, int np, float scale,
    float* __restrict__ out)
{
    const int tid = threadIdx.x;
    float s = 0.f;
    for (int i = tid; i < np; i += 256) s += partials[i];
#pragma unroll
    for (int off = 32; off > 0; off >>= 1)
        s += __shfl_down(s, off, 64);
    __shared__ float wsum[4];
    if ((tid & 63) == 0) wsum[tid >> 6] = s;
    __syncthreads();
    if (tid == 0) out[0] = (wsum[0] + wsum[1] + wsum[2] + wsum[3]) * scale;
}

// ---------------------------------------------------------------------------
extern "C" void kernel_launch(void* const* d_in, const int* in_sizes, int n_in,
                              void* d_out, int out_size, void* d_ws, size_t ws_size,
                              hipStream_t stream) {
    const float* fea0  = (const float*)d_in[0];
    const float* fea1  = (const float*)d_in[1];
    const float* fea2  = (const float*)d_in[2];
    const float* fea3  = (const float*)d_in[3];
    const float* W_mu  = (const float*)d_in[4];
    const float* b_mu  = (const float*)d_in[5];
    const float* W_var = (const float*)d_in[6];
    const float* b_var = (const float*)d_in[7];
    float* out = (float*)d_out;
    float* ws  = (float*)d_ws;

    if (ws_size >= WS_REQ) {
        // zero barrier + ticket counters (captured; runs every replay)
        hipMemsetAsync(ws + CNT_OFF, 0, 2 * sizeof(int), stream);
        ib_one<<<NPART, 256, 0, stream>>>(fea0, fea1, fea2, fea3,
                                          W_mu, b_mu, W_var, b_var, ws, out);
    } else {
        const int nblk = NSAMP / 4;
        ib_fused<<<dim3(nblk, NLAYER), 256, 0, stream>>>(
            fea0, fea1, fea2, fea3, W_mu, b_mu, W_var, b_var, ws);
        ib_final<<<1, 256, 0, stream>>>(ws, nblk * NLAYER,
                                        1.0f / (float)NSAMP, out);
    }
}

// Round 4
// 83.851 us; speedup vs baseline: 1.8496x; 1.8496x over previous
//
#include <hip/hip_runtime.h>
#include <math.h>

#define NSAMP 1024
#define DIM   64
#define NLAYER 3

#define JC 64                    // j rows per chunk (LDS tile)
#define JS (NSAMP / JC)          // 16 j-chunks
#define NT 64                    // n rows per block
#define RT 4                     // n rows per thread
#define NTILES (NSAMP / NT)      // 16 n-tiles
#define NPART (NTILES * JS * NLAYER)   // 768 blocks

#define MAGIC_HI 0x5AFE600Du

// ---------------------------------------------------------------------------
// ONE dispatch. Each block = (layer, ntile, jc). No grid barrier:
// the mu/var head is recomputed per block, per-thread-direct (each thread
// computes only the 16 mu/iv values it consumes). Completion detection is
// contention-free: one 8-byte {MAGIC|partial} store per block to its own
// slot; block 0 polls read-only, reduces in fixed order, resets slots to 0.
__global__ __launch_bounds__(256) void ib_mono(
    const float* __restrict__ fea0, const float* __restrict__ fea1,
    const float* __restrict__ fea2, const float* __restrict__ fea3,
    const float* __restrict__ W_mu, const float* __restrict__ b_mu,
    const float* __restrict__ W_var, const float* __restrict__ b_var,
    unsigned long long* __restrict__ pairs, float* __restrict__ out)
{
    const int b     = blockIdx.x;          // 0..767
    const int layer = b >> 8;
    const int sub   = b & 255;
    const int ntile = sub & 15;
    const int jc    = sub >> 4;
    const int tid   = threadIdx.x;
    const int q     = tid & 15;            // d-group: d0..d0+3
    const int rg    = tid >> 4;            // row-group: 4 rows
    const int d0    = q * 4;
    const int n0    = ntile * NT + rg * RT;

    const float* __restrict__ fr_p =
        (layer == 0) ? fea0 : (layer == 1) ? fea1 : fea2;   // reference
    const float* __restrict__ fs_p =
        (layer == 0) ? fea1 : (layer == 1) ? fea2 : fea3;   // student

    __shared__ float4 buf[JC][DIM / 4];    // 16 KB: fs tile, then fr chunks
    __shared__ float  wsum[4];

    // ---------------- phase A: stage fs n-tile, per-thread head -------------
    const float4* __restrict__ fsrc = (const float4*)(fs_p + ntile * NT * DIM);
#pragma unroll
    for (int t = 0; t < 4; ++t)
        ((float4*)buf)[tid + 256 * t] = fsrc[tid + 256 * t];
    __syncthreads();

    const float4* __restrict__ wmB = (const float4*)W_mu  + (layer * DIM + d0) * 16;
    const float4* __restrict__ wvB = (const float4*)W_var + (layer * DIM + d0) * 16;

    float4 am[RT], av[RT];
#pragma unroll
    for (int r = 0; r < RT; ++r) {
        am[r] = make_float4(0.f, 0.f, 0.f, 0.f);
        av[r] = make_float4(0.f, 0.f, 0.f, 0.f);
    }
#pragma unroll
    for (int k4 = 0; k4 < 16; ++k4) {
        float4 f[RT];
#pragma unroll
        for (int r = 0; r < RT; ++r) f[r] = buf[rg * RT + r][k4];
        const float4 w0 = wmB[k4];           // W_mu row d0+0, cols 4k4..
        const float4 w1 = wmB[16 + k4];
        const float4 w2 = wmB[32 + k4];
        const float4 w3 = wmB[48 + k4];
        const float4 v0 = wvB[k4];
        const float4 v1 = wvB[16 + k4];
        const float4 v2 = wvB[32 + k4];
        const float4 v3 = wvB[48 + k4];
#pragma unroll
        for (int r = 0; r < RT; ++r) {
            am[r].x = fmaf(f[r].x, w0.x, am[r].x); am[r].x = fmaf(f[r].y, w0.y, am[r].x);
            am[r].x = fmaf(f[r].z, w0.z, am[r].x); am[r].x = fmaf(f[r].w, w0.w, am[r].x);
            am[r].y = fmaf(f[r].x, w1.x, am[r].y); am[r].y = fmaf(f[r].y, w1.y, am[r].y);
            am[r].y = fmaf(f[r].z, w1.z, am[r].y); am[r].y = fmaf(f[r].w, w1.w, am[r].y);
            am[r].z = fmaf(f[r].x, w2.x, am[r].z); am[r].z = fmaf(f[r].y, w2.y, am[r].z);
            am[r].z = fmaf(f[r].z, w2.z, am[r].z); am[r].z = fmaf(f[r].w, w2.w, am[r].z);
            am[r].w = fmaf(f[r].x, w3.x, am[r].w); am[r].w = fmaf(f[r].y, w3.y, am[r].w);
            am[r].w = fmaf(f[r].z, w3.z, am[r].w); am[r].w = fmaf(f[r].w, w3.w, am[r].w);

            av[r].x = fmaf(f[r].x, v0.x, av[r].x); av[r].x = fmaf(f[r].y, v0.y, av[r].x);
            av[r].x = fmaf(f[r].z, v0.z, av[r].x); av[r].x = fmaf(f[r].w, v0.w, av[r].x);
            av[r].y = fmaf(f[r].x, v1.x, av[r].y); av[r].y = fmaf(f[r].y, v1.y, av[r].y);
            av[r].y = fmaf(f[r].z, v1.z, av[r].y); av[r].y = fmaf(f[r].w, v1.w, av[r].y);
            av[r].z = fmaf(f[r].x, v2.x, av[r].z); av[r].z = fmaf(f[r].y, v2.y, av[r].z);
            av[r].z = fmaf(f[r].z, v2.z, av[r].z); av[r].z = fmaf(f[r].w, v2.w, av[r].z);
            av[r].w = fmaf(f[r].x, v3.x, av[r].w); av[r].w = fmaf(f[r].y, v3.y, av[r].w);
            av[r].w = fmaf(f[r].z, v3.z, av[r].w); av[r].w = fmaf(f[r].w, v3.w, av[r].w);
        }
    }

    const float4 bm = ((const float4*)b_mu)[layer * 16 + q];
    const float4 bv = ((const float4*)b_var)[layer * 16 + q];
    float4 mu4[RT], iv4[RT];
#pragma unroll
    for (int r = 0; r < RT; ++r) {
        mu4[r].x = am[r].x + bm.x; mu4[r].y = am[r].y + bm.y;
        mu4[r].z = am[r].z + bm.z; mu4[r].w = am[r].w + bm.w;
        float xs[4] = { av[r].x + bv.x, av[r].y + bv.y,
                        av[r].z + bv.z, av[r].w + bv.w };
        float iv[4];
#pragma unroll
        for (int c = 0; c < 4; ++c) {
            const float x  = xs[c];
            const float sp = fmaxf(x, 0.f) + log1pf(expf(-fabsf(x)));
            iv[c] = 1.0f / (sp * 0.1f + 1e-6f);
        }
        iv4[r] = make_float4(iv[0], iv[1], iv[2], iv[3]);
    }

    // ---------------- phase B: stage fr j-chunk, pairwise -------------------
    __syncthreads();   // done reading fs from buf
    const float4* __restrict__ frsrc = (const float4*)(fr_p + jc * JC * DIM);
#pragma unroll
    for (int t = 0; t < 4; ++t)
        ((float4*)buf)[tid + 256 * t] = frsrc[tid + 256 * t];
    __syncthreads();

    float4 ps[RT];
#pragma unroll
    for (int r = 0; r < RT; ++r) ps[r] = make_float4(0.f, 0.f, 0.f, 0.f);

#pragma unroll 8
    for (int j = 0; j < JC; ++j) {
        const float4 f = buf[j][q];
#pragma unroll
        for (int r = 0; r < RT; ++r) {
            ps[r].x += fabsf(f.x - mu4[r].x);
            ps[r].y += fabsf(f.y - mu4[r].y);
            ps[r].z += fabsf(f.z - mu4[r].z);
            ps[r].w += fabsf(f.w - mu4[r].w);
        }
    }

    const float inv_n = 1.0f / (float)NSAMP;
    float s = 0.f;
    if (jc == 0) {
        // positive term once per (n,d): this block's j-chunk index is 0
#pragma unroll
        for (int r = 0; r < RT; ++r) {
            const float4 a = *(const float4*)(fr_p + (n0 + r) * DIM + d0);
            s += (ps[r].x * inv_n - fabsf(mu4[r].x - a.x)) * iv4[r].x;
            s += (ps[r].y * inv_n - fabsf(mu4[r].y - a.y)) * iv4[r].y;
            s += (ps[r].z * inv_n - fabsf(mu4[r].z - a.z)) * iv4[r].z;
            s += (ps[r].w * inv_n - fabsf(mu4[r].w - a.w)) * iv4[r].w;
        }
    } else {
#pragma unroll
        for (int r = 0; r < RT; ++r) {
            s += ps[r].x * inv_n * iv4[r].x;
            s += ps[r].y * inv_n * iv4[r].y;
            s += ps[r].z * inv_n * iv4[r].z;
            s += ps[r].w * inv_n * iv4[r].w;
        }
    }

    // deterministic block reduction
#pragma unroll
    for (int off = 32; off > 0; off >>= 1)
        s += __shfl_down(s, off, 64);
    if ((tid & 63) == 0) wsum[tid >> 6] = s;
    __syncthreads();

    // one contention-free 8B store per block: {MAGIC_HI | partial bits}
    if (tid == 0) {
        const float p = wsum[0] + wsum[1] + wsum[2] + wsum[3];
        const unsigned long long v =
            ((unsigned long long)MAGIC_HI << 32) |
            (unsigned long long)__float_as_uint(p);
        __hip_atomic_store(&pairs[b], v, __ATOMIC_RELAXED,
                           __HIP_MEMORY_SCOPE_AGENT);
    }

    // ---------------- block 0: poll (read-only), reduce, reset --------------
    if (b == 0) {
        __syncthreads();   // wsum reuse below
        unsigned long long v[3];
#pragma unroll
        for (int t = 0; t < 3; ++t) {
            unsigned long long* slot = &pairs[tid + t * 256];
            for (;;) {
                const unsigned long long x =
                    __hip_atomic_load(slot, __ATOMIC_RELAXED,
                                      __HIP_MEMORY_SCOPE_AGENT);
                if ((unsigned)(x >> 32) == MAGIC_HI) { v[t] = x; break; }
                __builtin_amdgcn_s_sleep(1);
            }
        }
        // reset slots so no MAGIC state persists across calls
#pragma unroll
        for (int t = 0; t < 3; ++t)
            __hip_atomic_store(&pairs[tid + t * 256], 0ull, __ATOMIC_RELAXED,
                               __HIP_MEMORY_SCOPE_AGENT);
        // fixed-order sum: slot order tid, tid+256, tid+512, then fixed tree
        float s2 = __uint_as_float((unsigned)v[0])
                 + __uint_as_float((unsigned)v[1])
                 + __uint_as_float((unsigned)v[2]);
#pragma unroll
        for (int off = 32; off > 0; off >>= 1)
            s2 += __shfl_down(s2, off, 64);
        if ((tid & 63) == 0) wsum[tid >> 6] = s2;
        __syncthreads();
        if (tid == 0)
            out[0] = (wsum[0] + wsum[1] + wsum[2] + wsum[3]) * inv_n;
    }
}

// ---------------------------------------------------------------------------
// fallback path (tiny ws): round-1 fused kernel + final reduce
__global__ __launch_bounds__(256) void ib_fused(
    const float* __restrict__ fea0, const float* __restrict__ fea1,
    const float* __restrict__ fea2, const float* __restrict__ fea3,
    const float* __restrict__ W_mu, const float* __restrict__ b_mu,
    const float* __restrict__ W_var, const float* __restrict__ b_var,
    float* __restrict__ partials)
{
    const int layer = blockIdx.y;
    const float* feas[4] = {fea0, fea1, fea2, fea3};
    const float* __restrict__ fr_p = feas[layer];
    const float* __restrict__ fs_p = feas[layer + 1];

    const int tid = threadIdx.x;
    const int d   = tid & 63;
    const int nl  = tid >> 6;
    const int n   = blockIdx.x * 4 + nl;

    __shared__ float fs[4][DIM];
    __shared__ float fr[JC][DIM];
    __shared__ float wsum[4];

    fs[nl][d] = fs_p[n * DIM + d];
    __syncthreads();

    const float* __restrict__ wm = W_mu + (layer * DIM + d) * DIM;
    const float* __restrict__ wv = W_var + (layer * DIM + d) * DIM;
    float am = 0.f, av = 0.f;
#pragma unroll
    for (int k = 0; k < DIM; ++k) {
        const float f = fs[nl][k];
        am = fmaf(f, wm[k], am);
        av = fmaf(f, wv[k], av);
    }
    const float mu = am + b_mu[layer * DIM + d];
    const float x  = av + b_var[layer * DIM + d];
    const float sp  = fmaxf(x, 0.f) + log1pf(expf(-fabsf(x)));
    const float var = sp * 0.1f + 1e-6f;

    float psum = 0.f;
    for (int j0 = 0; j0 < NSAMP; j0 += JC) {
        __syncthreads();
#pragma unroll
        for (int t = 0; t < (JC * DIM) / 256; ++t) {
            const int l = tid + t * 256;
            fr[0][l] = fr_p[j0 * DIM + l];
        }
        __syncthreads();
#pragma unroll
        for (int j = 0; j < JC; ++j)
            psum += fabsf(fr[j][d] - mu);
    }

    const float frnd = fr_p[n * DIM + d];
    float t = (psum * (1.0f / NSAMP) - fabsf(mu - frnd)) / var;

#pragma unroll
    for (int off = 32; off > 0; off >>= 1)
        t += __shfl_down(t, off, 64);
    if ((tid & 63) == 0) wsum[tid >> 6] = t;
    __syncthreads();
    if (tid == 0)
        partials[blockIdx.y * gridDim.x + blockIdx.x] =
            wsum[0] + wsum[1] + wsum[2] + wsum[3];
}

__global__ __launch_bounds__(256) void ib_final(
    const float* __restrict__ partials, int np, float scale,
    float* __restrict__ out)
{
    const int tid = threadIdx.x;
    float s = 0.f;
    for (int i = tid; i < np; i += 256) s += partials[i];
#pragma unroll
    for (int off = 32; off > 0; off >>= 1)
        s += __shfl_down(s, off, 64);
    __shared__ float wsum[4];
    if ((tid & 63) == 0) wsum[tid >> 6] = s;
    __syncthreads();
    if (tid == 0) out[0] = (wsum[0] + wsum[1] + wsum[2] + wsum[3]) * scale;
}

// ---------------------------------------------------------------------------
extern "C" void kernel_launch(void* const* d_in, const int* in_sizes, int n_in,
                              void* d_out, int out_size, void* d_ws, size_t ws_size,
                              hipStream_t stream) {
    const float* fea0  = (const float*)d_in[0];
    const float* fea1  = (const float*)d_in[1];
    const float* fea2  = (const float*)d_in[2];
    const float* fea3  = (const float*)d_in[3];
    const float* W_mu  = (const float*)d_in[4];
    const float* b_mu  = (const float*)d_in[5];
    const float* W_var = (const float*)d_in[6];
    const float* b_var = (const float*)d_in[7];
    float* out = (float*)d_out;

    if (ws_size >= NPART * sizeof(unsigned long long)) {
        ib_mono<<<NPART, 256, 0, stream>>>(
            fea0, fea1, fea2, fea3, W_mu, b_mu, W_var, b_var,
            (unsigned long long*)d_ws, out);
    } else {
        float* ws = (float*)d_ws;
        const int nblk = NSAMP / 4;
        ib_fused<<<dim3(nblk, NLAYER), 256, 0, stream>>>(
            fea0, fea1, fea2, fea3, W_mu, b_mu, W_var, b_var, ws);
        ib_final<<<1, 256, 0, stream>>>(ws, nblk * NLAYER,
                                        1.0f / (float)NSAMP, out);
    }
}